// Round 7
// baseline (131.107 us; speedup 1.0000x reference)
//
#include <hip/hip_runtime.h>
#include <hip/hip_bf16.h>

#define MTOK 16384
#define DDIM 2048
#define NEXP 8
#define RNK 16
#define NC 128          // E*R down-projection columns
#define NW 160          // padded GEMM1 N: 128 h + 8 logits + 24 zero pad
#define NT3 (DDIM / 64) // 32 K-steps of 64

typedef __attribute__((ext_vector_type(8))) short bf16x8;
typedef __attribute__((ext_vector_type(4))) short short4v;
typedef __attribute__((ext_vector_type(4))) float f32x4;

typedef __attribute__((address_space(1))) const void gv_t;
typedef __attribute__((address_space(3))) void lv_t;

__device__ __forceinline__ short f2b(float f) {
  unsigned u = __float_as_uint(f);
  u += 0x7fffu + ((u >> 16) & 1u);   // round-to-nearest-even
  return (short)(u >> 16);
}

// ---------------- K0: weight prep (fp32 -> bf16, transposed layouts) -------
// WdT pre-swizzled per 64-elem K-tile: linear 16B-slot s holds logical slot
// s^(n&7) -> linear global_load_lds + swizzled ds_read_b128 is conflict-free.
// Logical WdT[n][k]: n<128 -> down[n>>4][k][n&15]; 128..135 -> rw[n-128][k]; else 0
// UT[c][k]: up[c>>4][c&15][k-index?]  -- UT[c][kc] = up[c>>4][c&15][? ] see below
// UT[c][j] for c in [0,2048), j in [0,128): B-operand (N x K) of phase 2:
//   output col c, rank-k j -> up[j>>4... wait: K-dim of phase2 = NC=128 (e,r).
//   UT[c][j] = up[(j>>4)][j&15][c]  (expert e=j>>4, rank r=j&15, out-dim c)
__global__ __launch_bounds__(256) void prep_k(const float* __restrict__ rw,
                                              const float* __restrict__ down,
                                              const float* __restrict__ up,
                                              short* __restrict__ WdT,
                                              short* __restrict__ UT) {
  int i = blockIdx.x * 256 + threadIdx.x;
  const int NWD = NW * DDIM;          // 327680
  const int NUT = DDIM * NC;          // 262144
  if (i < NWD) {
    int n = i / DDIM, k = i % DDIM;
    int s = (k >> 3) & 7;
    int src_k = (k & ~0x3F) | ((s ^ (n & 7)) << 3) | (k & 7);
    float v = 0.f;
    if (n < NC)             v = down[((n >> 4) * DDIM + src_k) * RNK + (n & 15)];
    else if (n < NC + NEXP) v = rw[(n - NC) * DDIM + src_k];
    WdT[i] = f2b(v);
  } else if (i < NWD + NUT) {
    int u = i - NWD;
    int c = u >> 7, j = u & 127;      // UT[c][j]
    UT[u] = f2b(up[((j >> 4) * RNK + (j & 15)) * DDIM + c]);
  }
}

// ---------------- Fused: GEMM1 + routing + GEMM2 + residual ----------------
// 256 blocks x 512 thr (8 waves), BM=64, full K. Counted-vmcnt pipeline:
// per wave per step: A=2 global loads, B=2-3 global_load_lds; steady-state
// s_waitcnt vmcnt(4) leaves exactly step-(t+2)'s ops in flight (both groups).
__global__ __launch_bounds__(512, 2) void fused_k(const float* __restrict__ X,
                                                  const short* __restrict__ WdT,
                                                  const short* __restrict__ UT,
                                                  float* __restrict__ Out) {
  __shared__ short Al[2][64][72];      // 18432 B (+8 pad)
  __shared__ short Bl[2][160 * 64];    // 40960 B linear; reused as eps in ph2
  __shared__ short HwS[64][136];       // 17408 B scaled h (bf16)
  __shared__ float lg[64][8];
  __shared__ float wv[64][8];
  const int tid = threadIdx.x;
  const int lane = tid & 63;
  const int w = tid >> 6;              // 0..7
  const int gm0 = blockIdx.x * 64;
  const int wr = (w & 3) * 16;         // phase-1 wave row base
  const int wc = (w >> 2) * 80;        // phase-1 wave col base (5 frags)
  const int lr = lane & 15;
  const int lk = (lane >> 4) * 8;

  // ---------------- phase 1: h/logits = X @ WdT^T --------------------------
  f32x4 acc[5];
#pragma unroll
  for (int n = 0; n < 5; ++n) acc[n] = (f32x4){0.f, 0.f, 0.f, 0.f};

  float4 aR[2][2];   // two A staging sets (2 K-steps in flight)

  auto loadA = [&](int k0, int s) {
#pragma unroll
    for (int i2 = 0; i2 < 2; ++i2) {
      int f = tid + 512 * i2;          // 1024 chunks: 64 rows x 16 float4
      int row = f >> 4, c4 = f & 15;
      aR[s][i2] = *(const float4*)(X + (size_t)(gm0 + row) * DDIM + k0 + c4 * 4);
    }
  };
  auto issueB = [&](int buf, int k0) {
    // 1280 16B-units = 20 wave-calls; wave w takes calls {w, 8+w, 16+w (<20)}
#pragma unroll
    for (int j = 0; j < 3; ++j) {
      int call = j * 8 + w;
      if (call < 20) {
        int u = call * 64 + lane;
        const short* g = WdT + (size_t)(u >> 3) * DDIM + k0 + (u & 7) * 8;
        short* l = &Bl[buf][call * 512];   // wave-uniform base
        __builtin_amdgcn_global_load_lds((gv_t*)g, (lv_t*)l, 16, 0, 0);
      }
    }
  };
  auto writeA = [&](int buf, int s) {
#pragma unroll
    for (int i2 = 0; i2 < 2; ++i2) {
      int f = tid + 512 * i2;
      int row = f >> 4, c4 = f & 15;
      short4v v;
      v.x = f2b(aR[s][i2].x); v.y = f2b(aR[s][i2].y);
      v.z = f2b(aR[s][i2].z); v.w = f2b(aR[s][i2].w);
      *(short4v*)&Al[buf][row][c4 * 4] = v;
    }
  };
  auto compute = [&](int buf) {
#pragma unroll
    for (int kk2 = 0; kk2 < 2; ++kk2) {
      const int kk = kk2 * 32;
      bf16x8 a = *(const bf16x8*)&Al[buf][wr + lr][kk + lk];
      bf16x8 b[5];
#pragma unroll
      for (int n = 0; n < 5; ++n) {
        int row = wc + n * 16 + lr;
        int sl = ((kk >> 3) + (lane >> 4)) ^ (row & 7);   // swizzled 16B slot
        b[n] = *(const bf16x8*)&Bl[buf][row * 64 + sl * 8];
      }
#pragma unroll
      for (int n = 0; n < 5; ++n)
        acc[n] = __builtin_amdgcn_mfma_f32_16x16x32_bf16(a, b[n], acc[n], 0, 0, 0);
    }
  };

  // ---- prologue ----
  loadA(0, 0);
  issueB(0, 0);
  loadA(64, 1);
  issueB(1, 64);
  asm volatile("s_waitcnt vmcnt(4)" ::: "memory");   // A(0),B(0) retired (both wave groups)
  __builtin_amdgcn_sched_barrier(0);
  writeA(0, 0);
  asm volatile("s_waitcnt lgkmcnt(0)" ::: "memory");
  __builtin_amdgcn_sched_barrier(0);
  __builtin_amdgcn_s_barrier();

  // ---- main loop (fully unrolled; static buffer indices) ----
#pragma unroll
  for (int t = 0; t < NT3; ++t) {
    if (t + 2 < NT3) loadA((t + 2) * 64, t & 1);      // A(t+2) into freed set
    compute(t & 1);
    asm volatile("s_waitcnt lgkmcnt(0)" ::: "memory");
    __builtin_amdgcn_s_barrier();                     // all waves done with buf t&1
    __builtin_amdgcn_sched_barrier(0);
    if (t + 2 < NT3) issueB(t & 1, (t + 2) * 64);     // B(t+2) into freed buf
    if (t + 1 < NT3) {
      if (t + 2 < NT3)
        asm volatile("s_waitcnt vmcnt(4)" ::: "memory");  // retire step t+1 ops
      else
        asm volatile("s_waitcnt vmcnt(0)" ::: "memory");  // tail
      __builtin_amdgcn_sched_barrier(0);
      writeA((t + 1) & 1, (t + 1) & 1);
      asm volatile("s_waitcnt lgkmcnt(0)" ::: "memory");
      __builtin_amdgcn_sched_barrier(0);
    }
    __builtin_amdgcn_s_barrier();                     // publish step t+1
  }

  // ---------------- routing: top2 softmax on logits (cols 128-135) ---------
  // Waves 4-7 (wc=80) hold logits in frag n=3 (cols 128-143), lanes lr<8.
  if (w >= 4 && lr < 8) {
#pragma unroll
    for (int r = 0; r < 4; ++r)
      lg[wr + (lane >> 4) * 4 + r][lr] = acc[3][r];
  }
  __syncthreads();
  if (tid < 64) {
    float b0 = -1e30f, b1 = -1e30f;
    int i0 = 0, i1 = 0;
#pragma unroll
    for (int e = 0; e < 8; ++e) {
      float v = lg[tid][e];
      if (v > b0) { b1 = b0; i1 = i0; b0 = v; i0 = e; }   // lax.top_k tie-break
      else if (v > b1) { b1 = v; i1 = e; }
    }
    float ex = __expf(b1 - b0);
    float inv = 1.f / (1.f + ex);
#pragma unroll
    for (int e = 0; e < 8; ++e)
      wv[tid][e] = (e == i0) ? inv : ((e == i1) ? ex * inv : 0.f);
  }
  __syncthreads();

  // scale h -> HwS bf16. Waves 0-3: cols 0-79 (n<5); waves 4-7: 80-127 (n<3).
  {
    const int cmax = (w < 4) ? 5 : 3;
#pragma unroll
    for (int n = 0; n < 5; ++n) {
      if (n >= cmax) break;
      int col = wc + n * 16 + lr;
#pragma unroll
      for (int r = 0; r < 4; ++r) {
        int row = wr + (lane >> 4) * 4 + r;
        HwS[row][col] = f2b(acc[n][r] * wv[row][col >> 4]);
      }
    }
  }
  __syncthreads();

  // ---------------- phase 2: Out = X + HwS @ UT^T --------------------------
  // Each wave: 64 rows x 256 cols [w*256,(w+1)*256). B streams from L2 UT.
  bf16x8 af[4][4];
#pragma unroll
  for (int m = 0; m < 4; ++m)
#pragma unroll
    for (int kc = 0; kc < 4; ++kc)
      af[m][kc] = *(const bf16x8*)&HwS[m * 16 + lr][kc * 32 + lk];

  float* eps = (float*)&Bl[0][0] + w * 1088;   // wave-private 16 rows x 68 f32
  const int cr = (lane >> 4) * 4;
  const int ncol0 = w * 256;
#pragma unroll 1
  for (int nb = 0; nb < 4; ++nb) {
    const int c0 = ncol0 + nb * 64;
    f32x4 acc2[4][4];
#pragma unroll
    for (int m = 0; m < 4; ++m)
#pragma unroll
      for (int nf = 0; nf < 4; ++nf) acc2[m][nf] = (f32x4){0.f, 0.f, 0.f, 0.f};
#pragma unroll
    for (int kc = 0; kc < 4; ++kc) {
      bf16x8 bfr[4];
#pragma unroll
      for (int nf = 0; nf < 4; ++nf)
        bfr[nf] = *(const bf16x8*)(UT + (size_t)(c0 + nf * 16 + lr) * NC + kc * 32 + lk);
#pragma unroll
      for (int m = 0; m < 4; ++m)
#pragma unroll
        for (int nf = 0; nf < 4; ++nf)
          acc2[m][nf] = __builtin_amdgcn_mfma_f32_16x16x32_bf16(af[m][kc], bfr[nf], acc2[m][nf], 0, 0, 0);
    }
    // per-m wave-private LDS transpose -> float4 residual + store
#pragma unroll 1
    for (int m = 0; m < 4; ++m) {
#pragma unroll
      for (int nf = 0; nf < 4; ++nf)
#pragma unroll
        for (int r = 0; r < 4; ++r)
          eps[(cr + r) * 68 + nf * 16 + lr] = acc2[m][nf][r];
#pragma unroll
      for (int j = 0; j < 4; ++j) {
        int row = (lane >> 4) + 4 * j;
        int c4 = lane & 15;
        float4 v = *(const float4*)&eps[row * 68 + c4 * 4];
        size_t idx = (size_t)(gm0 + m * 16 + row) * DDIM + c0 + c4 * 4;
        const float4 xv = *(const float4*)(X + idx);
        v.x += xv.x; v.y += xv.y; v.z += xv.z; v.w += xv.w;
        *(float4*)(Out + idx) = v;
      }
    }
  }
}

// ---------------------------------------------------------------------------
extern "C" void kernel_launch(void* const* d_in, const int* in_sizes, int n_in,
                              void* d_out, int out_size, void* d_ws, size_t ws_size,
                              hipStream_t stream) {
  const float* x    = (const float*)d_in[0];
  const float* rw   = (const float*)d_in[1];
  const float* down = (const float*)d_in[2];
  const float* up   = (const float*)d_in[3];
  float* out = (float*)d_out;

  char* ws = (char*)d_ws;
  short* WdT = (short*)ws;                 // 160*2048*2 = 655360 B
  short* UT  = (short*)(ws + 655360);      // 2048*128*2 = 524288 B

  prep_k<<<2304, 256, 0, stream>>>(rw, down, up, WdT, UT);
  fused_k<<<MTOK / 64, 512, 0, stream>>>(x, WdT, UT, out);   // 256 blocks
}

// Round 8
// 94.815 us; speedup vs baseline: 1.3828x; 1.3828x over previous
//
#include <hip/hip_runtime.h>
#include <hip/hip_bf16.h>

#define MTOK 16384
#define DDIM 2048
#define NEXP 8
#define RNK 16
#define NC 128          // E*R down-projection columns
#define NW 160          // padded GEMM1 N: 128 h + 8 logits + 24 zero pad
#define LOGIT0 128
#define KSPLIT 2
#define KLEN (DDIM / KSPLIT)   // 1024
#define BK1 32
#define NT (KLEN / BK1)        // 32 K-steps of 32
#define BM1 32                 // gemm1 rows per block

typedef __attribute__((ext_vector_type(8))) short bf16x8;
typedef __attribute__((ext_vector_type(4))) short short4v;
typedef __attribute__((ext_vector_type(4))) float f32x4;

typedef __attribute__((address_space(1))) const void gv_t;
typedef __attribute__((address_space(3))) void lv_t;

__device__ __forceinline__ short f2b(float f) {
  unsigned u = __float_as_uint(f);
  u += 0x7fffu + ((u >> 16) & 1u);   // round-to-nearest-even
  return (short)(u >> 16);
}
__device__ __forceinline__ float b2f(short s) {
  return __uint_as_float(((unsigned)(unsigned short)s) << 16);
}

// ---------------- K0: weight prep (fp32 -> bf16, transposed layouts) -------
// WdT pre-swizzled per 32-elem K-tile: linear 16B-slot s (0..3) holds logical
// slot s ^ ((n>>1)&3), so gemm1's linear global_load_lds + swizzled
// ds_read_b128 is ~2-way (free) instead of 8-way.
// Logical WdT[n][k]: n<128 -> down[n>>4][k][n&15]; 128..135 -> rw[n-128][k]; else 0
// UT[c][j]: up[j>>4][j&15][c]  (B-operand N x K for gemm2)
__global__ __launch_bounds__(256) void prep_k(const float* __restrict__ rw,
                                              const float* __restrict__ down,
                                              const float* __restrict__ up,
                                              short* __restrict__ WdT,
                                              short* __restrict__ UT) {
  int i = blockIdx.x * 256 + threadIdx.x;
  const int NWD = NW * DDIM;          // 327680
  const int NUT = DDIM * NC;          // 262144
  if (i < NWD) {
    int n = i / DDIM, k = i % DDIM;
    int s = (k >> 3) & 3;
    int src_k = (k & ~0x1F) | ((s ^ ((n >> 1) & 3)) << 3) | (k & 7);
    float v = 0.f;
    if (n < NC)             v = down[((n >> 4) * DDIM + src_k) * RNK + (n & 15)];
    else if (n < NC + NEXP) v = rw[(n - NC) * DDIM + src_k];
    WdT[i] = f2b(v);
  } else if (i < NWD + NUT) {
    int u = i - NWD;
    int c = u >> 7, j = u & 127;
    UT[u] = f2b(up[((j >> 4) * RNK + (j & 15)) * DDIM + c]);
  }
}

// ---------------- K1: GEMM1  Hp[ks][16384][160] (bf16) = X @ WdT^T ---------
// Split-K=2, BM=32, BK=32 -> grid 1024, LDS 25.6 KB -> 4 blocks/CU (16 w/CU).
// Counted-vmcnt 2-deep pipeline. Per wave per step: A=1 load, B=3 (w<2) or
// 2 (w>=2) global_load_lds. Steady wait vmcnt(4)/vmcnt(3), never 0.
__global__ __launch_bounds__(256, 4) void gemm1_k(const float* __restrict__ X,
                                                  const short* __restrict__ WdT,
                                                  short* __restrict__ Hp) {
  __shared__ short Al[2][BM1][40];     // 5120 B (+8 pad)
  __shared__ short Bl[2][160 * 32];    // 20480 B, linear for global_load_lds
  const int tid = threadIdx.x;
  const int lane = tid & 63;
  const int w = tid >> 6;
  const int gm0 = blockIdx.x * BM1;
  const int ks = blockIdx.y;
  const int kb = ks * KLEN;
  const int wr = (w & 1) * 16;         // wave row base (1 m-frag)
  const int wc = (w >> 1) * 80;        // wave col base (5 frags of 16)
  const int lr = lane & 15;
  const int lk = (lane >> 4) * 8;

  f32x4 acc[5];
#pragma unroll
  for (int n = 0; n < 5; ++n) acc[n] = (f32x4){0.f, 0.f, 0.f, 0.f};

  float4 aR[2];   // two A staging sets (2 K-steps in flight); 1 float4/thread

  auto loadA = [&](int k0, int s) {
    int row = tid >> 3, c4 = tid & 7;  // 32 rows x 8 float4-chunks
    aR[s] = *(const float4*)(X + (size_t)(gm0 + row) * DDIM + k0 + c4 * 4);
  };
  auto issueB = [&](int buf, int k0) {
    // 160x32 bf16 = 640 x 16B units = 10 wave-calls; wave w: calls {w,4+w,8+w<10}
#pragma unroll
    for (int j = 0; j < 3; ++j) {
      int call = j * 4 + w;
      if (call < 10) {
        int u = call * 64 + lane;
        const short* g = WdT + (size_t)(u >> 2) * DDIM + k0 + (u & 3) * 8;
        short* l = &Bl[buf][call * 512];   // wave-uniform base
        __builtin_amdgcn_global_load_lds((gv_t*)g, (lv_t*)l, 16, 0, 0);
      }
    }
  };
  auto writeA = [&](int buf, int s) {
    int row = tid >> 3, c4 = tid & 7;
    short4v v;
    v.x = f2b(aR[s].x); v.y = f2b(aR[s].y);
    v.z = f2b(aR[s].z); v.w = f2b(aR[s].w);
    *(short4v*)&Al[buf][row][c4 * 4] = v;
  };
  auto compute = [&](int buf) {
    bf16x8 a = *(const bf16x8*)&Al[buf][wr + lr][lk];
    bf16x8 b[5];
#pragma unroll
    for (int n = 0; n < 5; ++n) {
      int row = wc + n * 16 + lr;
      int sl = (lane >> 4) ^ ((row >> 1) & 3);   // swizzled 16B slot
      b[n] = *(const bf16x8*)&Bl[buf][row * 32 + sl * 8];
    }
#pragma unroll
    for (int n = 0; n < 5; ++n)
      acc[n] = __builtin_amdgcn_mfma_f32_16x16x32_bf16(a, b[n], acc[n], 0, 0, 0);
  };

  // ---- prologue (per-wave FIFO: A0, B0(3/2), A1, B1(3/2)) ----
  loadA(kb, 0);
  issueB(0, kb);
  loadA(kb + BK1, 1);
  issueB(1, kb + BK1);
  if (w < 2) { asm volatile("s_waitcnt vmcnt(7)" ::: "memory"); }   // A(0) done
  else       { asm volatile("s_waitcnt vmcnt(5)" ::: "memory"); }
  __builtin_amdgcn_sched_barrier(0);
  writeA(0, 0);
  if (w < 2) { asm volatile("s_waitcnt vmcnt(4)" ::: "memory"); }   // B(0) done
  else       { asm volatile("s_waitcnt vmcnt(3)" ::: "memory"); }
  asm volatile("s_waitcnt lgkmcnt(0)" ::: "memory");
  __builtin_amdgcn_sched_barrier(0);
  __builtin_amdgcn_s_barrier();

  // ---- main loop: fully unrolled, static buffer indices ----
#pragma unroll
  for (int t = 0; t < NT; ++t) {
    if (t + 2 < NT) loadA(kb + (t + 2) * BK1, t & 1);   // A(t+2)
    compute(t & 1);
    asm volatile("s_waitcnt lgkmcnt(0)" ::: "memory");
    __builtin_amdgcn_s_barrier();                       // buf t&1 free to refill
    __builtin_amdgcn_sched_barrier(0);
    if (t + 2 < NT) issueB(t & 1, kb + (t + 2) * BK1);  // B(t+2)
    if (t + 1 < NT) {
      if (t + 2 < NT) {
        if (w < 2) { asm volatile("s_waitcnt vmcnt(4)" ::: "memory"); }  // retire t+1
        else       { asm volatile("s_waitcnt vmcnt(3)" ::: "memory"); }
      } else {
        asm volatile("s_waitcnt vmcnt(0)" ::: "memory");                 // tail
      }
      __builtin_amdgcn_sched_barrier(0);
      writeA((t + 1) & 1, (t + 1) & 1);
      asm volatile("s_waitcnt lgkmcnt(0)" ::: "memory");
      __builtin_amdgcn_sched_barrier(0);
    }
    __builtin_amdgcn_s_barrier();                       // publish step t+1
  }

  short* Hq = Hp + (size_t)ks * MTOK * NW;
  const int cr = (lane >> 4) * 4;
#pragma unroll
  for (int n = 0; n < 5; ++n)
#pragma unroll
    for (int r = 0; r < 4; ++r) {
      int row = gm0 + wr + cr + r;
      int col = wc + n * 16 + lr;
      Hq[(size_t)row * NW + col] = f2b(acc[n][r]);
    }
}

// ---------------- K2: routing — sum split-K, top2 softmax, scale -> Hw -----
__global__ __launch_bounds__(256) void route_k(const short* __restrict__ Hp,
                                               short* __restrict__ Hw) {
  __shared__ float wv[64][8];
  const int tid = threadIdx.x;
  const int t0 = blockIdx.x * 64;
  const short* H0 = Hp;
  const short* H1 = Hp + (size_t)MTOK * NW;
  if (tid < 64) {
    int t = t0 + tid;
    uint4 l0 = *(const uint4*)(H0 + (size_t)t * NW + LOGIT0);
    uint4 l1 = *(const uint4*)(H1 + (size_t)t * NW + LOGIT0);
    const short* p0 = (const short*)&l0;
    const short* p1 = (const short*)&l1;
    float b0 = -1e30f, b1 = -1e30f;
    int i0 = 0, i1 = 0;
#pragma unroll
    for (int e = 0; e < 8; ++e) {
      float v = b2f(p0[e]) + b2f(p1[e]);
      if (v > b0) { b1 = b0; i1 = i0; b0 = v; i0 = e; }   // lax.top_k tie-break
      else if (v > b1) { b1 = v; i1 = e; }
    }
    float ex = __expf(b1 - b0);
    float inv = 1.f / (1.f + ex);
#pragma unroll
    for (int e = 0; e < 8; ++e)
      wv[tid][e] = (e == i0) ? inv : ((e == i1) ? ex * inv : 0.f);
  }
  __syncthreads();
  const int t = tid >> 2, q = tid & 3;     // token, col-quarter (32 cols)
  const short* a0 = H0 + (size_t)(t0 + t) * NW + q * 32;
  const short* a1 = H1 + (size_t)(t0 + t) * NW + q * 32;
  short* o = Hw + (size_t)(t0 + t) * NC + q * 32;
#pragma unroll
  for (int j = 0; j < 4; ++j) {
    uint4 v0 = *(const uint4*)(a0 + j * 8);
    uint4 v1 = *(const uint4*)(a1 + j * 8);
    const short* s0 = (const short*)&v0;
    const short* s1 = (const short*)&v1;
    short r[8];
    int cbase = q * 32 + j * 8;
#pragma unroll
    for (int e2 = 0; e2 < 8; ++e2) {
      float h = b2f(s0[e2]) + b2f(s1[e2]);
      r[e2] = f2b(h * wv[t][(cbase + e2) >> 4]);
    }
    *(uint4*)(o + j * 8) = *(uint4*)r;
  }
}

// ---------------- K3: GEMM2 + residual  Out = X + Hw @ U -------------------
// BM=128, BN=64, K=128 single stage. Epilogue transposes acc through each
// wave's PRIVATE LDS slice (== its own A rows, no barrier) for float4 I/O.
__global__ __launch_bounds__(256) void gemm2_k(const short* __restrict__ Hw,
                                               const short* __restrict__ UT,
                                               const float* __restrict__ X,
                                               float* __restrict__ Out) {
  __shared__ short Al[128][136];   // +8 pad, row stride 272B (34816 B)
  __shared__ short Bl[64][136];
  const int tid = threadIdx.x;
  const int lane = tid & 63;
  const int w = tid >> 6;
  const int gm0 = blockIdx.x * 128;
  const int n0 = blockIdx.y * 64;
  const int lr = lane & 15;
  const int lk = (lane >> 4) * 8;

#pragma unroll
  for (int i = 0; i < 8; ++i) {
    int f = tid + 256 * i;         // 128 rows x 16 chunks(16B)
    int row = f >> 4, c8 = f & 15;
    *(uint4*)&Al[row][c8 * 8] = *(const uint4*)(Hw + (size_t)(gm0 + row) * NC + c8 * 8);
  }
#pragma unroll
  for (int i = 0; i < 4; ++i) {
    int f = tid + 256 * i;         // 64 rows x 16 chunks
    int row = f >> 4, c8 = f & 15;
    *(uint4*)&Bl[row][c8 * 8] = *(const uint4*)(UT + (size_t)(n0 + row) * NC + c8 * 8);
  }
  __syncthreads();

  f32x4 acc[2][4];
#pragma unroll
  for (int m = 0; m < 2; ++m)
#pragma unroll
    for (int n = 0; n < 4; ++n) acc[m][n] = (f32x4){0.f, 0.f, 0.f, 0.f};

#pragma unroll
  for (int ks = 0; ks < 4; ++ks) {
    const int kk = ks * 32;
    bf16x8 a[2], b[4];
#pragma unroll
    for (int m = 0; m < 2; ++m) a[m] = *(const bf16x8*)&Al[w * 32 + m * 16 + lr][kk + lk];
#pragma unroll
    for (int n = 0; n < 4; ++n) b[n] = *(const bf16x8*)&Bl[n * 16 + lr][kk + lk];
#pragma unroll
    for (int m = 0; m < 2; ++m)
#pragma unroll
      for (int n = 0; n < 4; ++n)
        acc[m][n] = __builtin_amdgcn_mfma_f32_16x16x32_bf16(a[m], b[n], acc[m][n], 0, 0, 0);
  }

  // Epilogue: wave-private LDS transpose (bytes [w*8704, (w+1)*8704) ==
  // exactly Al rows [w*32, w*32+32), which only this wave read as A-frags).
  float* eps = (float*)&Al[0][0] + w * 2176;   // 32 rows x 68 floats
  const int cr = (lane >> 4) * 4;
#pragma unroll
  for (int m = 0; m < 2; ++m)
#pragma unroll
    for (int n = 0; n < 4; ++n)
#pragma unroll
      for (int r = 0; r < 4; ++r)
        eps[(m * 16 + cr + r) * 68 + n * 16 + lr] = acc[m][n][r];

#pragma unroll
  for (int j = 0; j < 8; ++j) {
    int c = lane + 64 * j;         // 512 float4-chunks: 32 rows x 16
    int rl = c >> 4, c4 = c & 15;
    float4 v = *(const float4*)&eps[rl * 68 + c4 * 4];
    size_t idx = (size_t)(gm0 + w * 32 + rl) * DDIM + n0 + c4 * 4;
    const float4 xv = *(const float4*)(X + idx);
    v.x += xv.x; v.y += xv.y; v.z += xv.z; v.w += xv.w;
    *(float4*)(Out + idx) = v;
  }
}

// ---------------------------------------------------------------------------
extern "C" void kernel_launch(void* const* d_in, const int* in_sizes, int n_in,
                              void* d_out, int out_size, void* d_ws, size_t ws_size,
                              hipStream_t stream) {
  const float* x    = (const float*)d_in[0];
  const float* rw   = (const float*)d_in[1];
  const float* down = (const float*)d_in[2];
  const float* up   = (const float*)d_in[3];
  float* out = (float*)d_out;

  char* ws = (char*)d_ws;
  short* WdT = (short*)ws;                          // 160*2048*2          =   655360 B
  short* UT  = (short*)(ws + 655360);               // 2048*128*2          =   524288 B
  short* Hp  = (short*)(ws + 1179648);              // 2*16384*160*2       = 10485760 B
  short* Hw  = (short*)(ws + 11665408);             // 16384*128*2         =  4194304 B
                                                    // total 15859712 B (proven fit)

  prep_k<<<2304, 256, 0, stream>>>(rw, down, up, WdT, UT);
  gemm1_k<<<dim3(MTOK / BM1, KSPLIT), 256, 0, stream>>>(x, WdT, Hp);        // 1024 blocks
  route_k<<<MTOK / 64, 256, 0, stream>>>(Hp, Hw);                           // 256 blocks
  gemm2_k<<<dim3(MTOK / 128, DDIM / 64), 256, 0, stream>>>(Hw, UT, x, out); // 4096 blocks
}